// Round 10
// baseline (2794.689 us; speedup 1.0000x reference)
//
#include <hip/hip_runtime.h>

// Residual VQ on MI355X (gfx950).
// z: [8, 32768, 32] f32; codebooks: [10, 512, 32] f32.
// Outputs (flat f32 in d_out): quantized [B,N,D], indices [B,N,Q] (as float),
// commit_loss [Q] (zeros).
//
// R10 = R9 (4 points/thread, half-codebook LDS staging, no-workspace,
// replay kernel) with the candidate loop rebuilt as a chunk-level software
// pipeline: R9 ran LDS and VALU as a SUM (750 cyc/candidate wall vs 352
// VALU + ~300 LDS) because the candidate registers were reused each
// iteration -- the next candidate's ds_reads couldn't issue until the
// current evals released the regs. Here the candidate lives in 8 named
// float4 chunks; chunk m's 16 FMAs are followed immediately by reloading
// c[m] with candidate k+1's chunk m (last-use-then-overwrite), so loads
// spread across the whole iteration and the in-order lgkm queue waits
// incrementally. Single buffer -> no R8-style 256-reg spill.
// Arithmetic: per accumulator slot s the j-order is s, s+8, s+16, s+24
// (mul first, then fma) -- identical op sequence to the proven numpy tree.
// dist = fma(-2,dot,rr)+cc, ascending-k strict-< first-min.

#define RVQ_B 8
#define RVQ_N 32768
#define RVQ_D 32
#define RVQ_Q 10
#define RVQ_C 512

static constexpr int  NPTS     = RVQ_B * RVQ_N;             // 262144
static constexpr long IDX_OFF  = (long)NPTS * RVQ_D;        // 8388608
static constexpr long LOSS_OFF = IDX_OFF + (long)NPTS * RVQ_Q;
static constexpr int  HALF     = RVQ_C / 2;                 // 256 codewords

typedef __attribute__((ext_vector_type(32))) float f32x32;

// ---------------------------------------------------------------------------
__device__ __forceinline__ float dot_self(const f32x32& v) {
    float a[8];
#pragma unroll
    for (int j = 0; j < 8; ++j) a[j] = v[j] * v[j];
#pragma unroll
    for (int j = 8; j < RVQ_D; ++j) a[j & 7] = fmaf(v[j], v[j], a[j & 7]);
    return ((a[0] + a[1]) + (a[2] + a[3])) + ((a[4] + a[5]) + (a[6] + a[7]));
}

// bit-exact straight-through residual update: qst = r + (c - r); r' = r - qst
__device__ __forceinline__ f32x32 st_update(const f32x32& r, const f32x32& g) {
    const f32x32 t   = g - r;
    const f32x32 qst = r + t;
    return r - qst;
}

// ---------------------------------------------------------------------------
// Kernel 1: argmin search, 4 points/thread, half-codebook staged in LDS,
// chunk-level software-pipelined candidate stream.
__global__ __launch_bounds__(256, 1) void rvq_search(const float* __restrict__ z,
                                                     const float* __restrict__ cb,
                                                     float* __restrict__ out) {
    __shared__ __align__(128) float scb[HALF * RVQ_D];   // 32 KB
    __shared__ float snorm[HALF];                        // 1 KB

    const int  t  = blockIdx.x * 256 + threadIdx.x;   // 65536 threads
    const long p0 = (long)t * 4;

    const f32x32* zv = (const f32x32*)(z + p0 * RVQ_D);
    f32x32 r0 = zv[0], r1 = zv[1], r2 = zv[2], r3 = zv[3];

#pragma unroll 1
    for (int q = 0; q < RVQ_Q; ++q) {
        const f32x32* cv   = (const f32x32*)(cb + (long)q * RVQ_C * RVQ_D);
        const float4* cbq4 = (const float4*)(cb + (long)q * RVQ_C * RVQ_D);

        const float rr0 = dot_self(r0), rr1 = dot_self(r1);
        const float rr2 = dot_self(r2), rr3 = dot_self(r3);

        float best0 = __builtin_inff(), best1 = __builtin_inff();
        float best2 = __builtin_inff(), best3 = __builtin_inff();
        int b0 = 0, b1 = 0, b2 = 0, b3 = 0;

#pragma unroll 1
        for (int h = 0; h < 2; ++h) {
            __syncthreads();   // prior half/stage reads complete before overwrite
            // ---- stage 256 codewords -> LDS (coalesced float4, stride-1)
#pragma unroll
            for (int i = 0; i < 8; ++i) {
                const int idx = threadIdx.x + 256 * i;   // 2048 float4 = 32 KB
                ((float4*)scb)[idx] = cbq4[h * (HALF * 8) + idx];
            }
            // ---- norms (bit-exact numpy tree, pure function of cb)
            snorm[threadIdx.x] = dot_self(cv[h * HALF + threadIdx.x]);
            __syncthreads();

            const float4* sv4 = (const float4*)scb;
            const int kg0 = h * HALF;

            // prologue: candidate 0's chunks + norm
            float4 c[8];
#pragma unroll
            for (int m = 0; m < 8; ++m) c[m] = sv4[m];
            float ccCur = snorm[0];

#pragma unroll 1
            for (int k = 0; k < HALF; ++k) {
                const int kn = (k + 1) & (HALF - 1);   // wrap: dead on last iter
                const float4* nx = sv4 + kn * 8;

                float a0[8], a1[8], a2[8], a3[8];

                // chunk m: 16 FMAs (4 points), then reload c[m] for k+1.
                // acc slot s=4*(m&1)+t receives j=4m+t; per-slot j order is
                // s, s+8, s+16, s+24 (mul first) == proven numpy tree.
#pragma unroll
                for (int m = 0; m < 8; ++m) {
                    const float4 cm = c[m];
                    const int s  = 4 * (m & 1);
                    const int j0 = 4 * m;
                    if (m < 2) {
                        a0[s+0] = r0[j0+0]*cm.x; a0[s+1] = r0[j0+1]*cm.y;
                        a0[s+2] = r0[j0+2]*cm.z; a0[s+3] = r0[j0+3]*cm.w;
                        a1[s+0] = r1[j0+0]*cm.x; a1[s+1] = r1[j0+1]*cm.y;
                        a1[s+2] = r1[j0+2]*cm.z; a1[s+3] = r1[j0+3]*cm.w;
                        a2[s+0] = r2[j0+0]*cm.x; a2[s+1] = r2[j0+1]*cm.y;
                        a2[s+2] = r2[j0+2]*cm.z; a2[s+3] = r2[j0+3]*cm.w;
                        a3[s+0] = r3[j0+0]*cm.x; a3[s+1] = r3[j0+1]*cm.y;
                        a3[s+2] = r3[j0+2]*cm.z; a3[s+3] = r3[j0+3]*cm.w;
                    } else {
                        a0[s+0]=fmaf(r0[j0+0],cm.x,a0[s+0]); a0[s+1]=fmaf(r0[j0+1],cm.y,a0[s+1]);
                        a0[s+2]=fmaf(r0[j0+2],cm.z,a0[s+2]); a0[s+3]=fmaf(r0[j0+3],cm.w,a0[s+3]);
                        a1[s+0]=fmaf(r1[j0+0],cm.x,a1[s+0]); a1[s+1]=fmaf(r1[j0+1],cm.y,a1[s+1]);
                        a1[s+2]=fmaf(r1[j0+2],cm.z,a1[s+2]); a1[s+3]=fmaf(r1[j0+3],cm.w,a1[s+3]);
                        a2[s+0]=fmaf(r2[j0+0],cm.x,a2[s+0]); a2[s+1]=fmaf(r2[j0+1],cm.y,a2[s+1]);
                        a2[s+2]=fmaf(r2[j0+2],cm.z,a2[s+2]); a2[s+3]=fmaf(r2[j0+3],cm.w,a2[s+3]);
                        a3[s+0]=fmaf(r3[j0+0],cm.x,a3[s+0]); a3[s+1]=fmaf(r3[j0+1],cm.y,a3[s+1]);
                        a3[s+2]=fmaf(r3[j0+2],cm.z,a3[s+2]); a3[s+3]=fmaf(r3[j0+3],cm.w,a3[s+3]);
                    }
                    c[m] = nx[m];   // software pipeline: reload after last use
                }
                const float ccNxt = snorm[kn];

                {
                    const float dot = ((a0[0]+a0[1])+(a0[2]+a0[3]))+((a0[4]+a0[5])+(a0[6]+a0[7]));
                    const float dist = fmaf(-2.0f, dot, rr0) + ccCur;
                    if (dist < best0) { best0 = dist; b0 = kg0 + k; }
                }
                {
                    const float dot = ((a1[0]+a1[1])+(a1[2]+a1[3]))+((a1[4]+a1[5])+(a1[6]+a1[7]));
                    const float dist = fmaf(-2.0f, dot, rr1) + ccCur;
                    if (dist < best1) { best1 = dist; b1 = kg0 + k; }
                }
                {
                    const float dot = ((a2[0]+a2[1])+(a2[2]+a2[3]))+((a2[4]+a2[5])+(a2[6]+a2[7]));
                    const float dist = fmaf(-2.0f, dot, rr2) + ccCur;
                    if (dist < best2) { best2 = dist; b2 = kg0 + k; }
                }
                {
                    const float dot = ((a3[0]+a3[1])+(a3[2]+a3[3]))+((a3[4]+a3[5])+(a3[6]+a3[7]));
                    const float dist = fmaf(-2.0f, dot, rr3) + ccCur;
                    if (dist < best3) { best3 = dist; b3 = kg0 + k; }
                }
                ccCur = ccNxt;
            }
        }

        // indices (as float, layout [B,N,Q])
        out[IDX_OFF + (p0 + 0) * RVQ_Q + q] = (float)b0;
        out[IDX_OFF + (p0 + 1) * RVQ_Q + q] = (float)b1;
        out[IDX_OFF + (p0 + 2) * RVQ_Q + q] = (float)b2;
        out[IDX_OFF + (p0 + 3) * RVQ_Q + q] = (float)b3;

        // gather chosen codewords from global (R7-proven), update residuals
        const f32x32 g0 = cv[b0];
        const f32x32 g1 = cv[b1];
        const f32x32 g2 = cv[b2];
        const f32x32 g3 = cv[b3];

        r0 = st_update(r0, g0);
        r1 = st_update(r1, g1);
        r2 = st_update(r2, g2);
        r3 = st_update(r3, g3);
    }
}

// ---------------------------------------------------------------------------
// Kernel 2: replay the straight-through chain from stored indices; writes
// quantized + commit_loss. Bit-identical op order to the reference.
// (Proven pre+post-timing in R3/R4/R5/R7/R8/R9.)
__global__ __launch_bounds__(256) void rvq_replay(const float* __restrict__ z,
                                                  const float* __restrict__ cb,
                                                  float* __restrict__ out) {
    const int p = blockIdx.x * 256 + threadIdx.x;

    float r[RVQ_D], oacc[RVQ_D];
    {
        const float4* zp = (const float4*)(z + (long)p * RVQ_D);
#pragma unroll
        for (int w = 0; w < 8; ++w) {
            const float4 v = zp[w];
            r[w * 4 + 0] = v.x; r[w * 4 + 1] = v.y;
            r[w * 4 + 2] = v.z; r[w * 4 + 3] = v.w;
        }
    }
#pragma unroll
    for (int d = 0; d < RVQ_D; ++d) oacc[d] = 0.0f;

#pragma unroll 1
    for (int q = 0; q < RVQ_Q; ++q) {
        const int idx = (int)out[IDX_OFF + (long)p * RVQ_Q + q];
        const float4* cwb = (const float4*)(cb + ((long)q * RVQ_C + idx) * RVQ_D);
        float cwv[RVQ_D];
#pragma unroll
        for (int w = 0; w < 8; ++w) {
            const float4 v = cwb[w];
            cwv[w * 4 + 0] = v.x; cwv[w * 4 + 1] = v.y;
            cwv[w * 4 + 2] = v.z; cwv[w * 4 + 3] = v.w;
        }
#pragma unroll
        for (int d = 0; d < RVQ_D; ++d) {
            const float qst = r[d] + (cwv[d] - r[d]);
            oacc[d] += qst;
            r[d] = r[d] - qst;
        }
    }

    float4* qo = (float4*)(out + (long)p * RVQ_D);
#pragma unroll
    for (int w = 0; w < 8; ++w) {
        float4 v;
        v.x = oacc[w * 4 + 0]; v.y = oacc[w * 4 + 1];
        v.z = oacc[w * 4 + 2]; v.w = oacc[w * 4 + 3];
        qo[w] = v;
    }

    if (p < RVQ_Q) out[LOSS_OFF + p] = 0.0f;
}

// ---------------------------------------------------------------------------
extern "C" void kernel_launch(void* const* d_in, const int* in_sizes, int n_in,
                              void* d_out, int out_size, void* d_ws, size_t ws_size,
                              hipStream_t stream) {
    const float* z  = (const float*)d_in[0];
    const float* cb = (const float*)d_in[1];
    float* out = (float*)d_out;
    (void)d_ws; (void)ws_size;  // no workspace (R6 post-timing lesson)

    rvq_search<<<NPTS / 4 / 256, 256, 0, stream>>>(z, cb, out);
    rvq_replay<<<NPTS / 256, 256, 0, stream>>>(z, cb, out);
}

// Round 11
// 1555.205 us; speedup vs baseline: 1.7970x; 1.7970x over previous
//
#include <hip/hip_runtime.h>

// Residual VQ on MI355X (gfx950) — MFMA distance engine with exact rescue.
// z: [8, 32768, 32] f32; codebooks: [10, 512, 32] f32.
// Outputs (flat f32 in d_out): quantized [B,N,D], indices [B,N,Q] (as float),
// commit_loss [Q] (zeros).
//
// R11: the VALU family (R7-R10) is capped at ~735 us search (344 wave-instr/
// point-stage, no fp32 MFMA). Here dots go to matrix cores via 2-term bf16
// split: s=-2r=sh+sl, c=ch+cl; d_approx = mfma(sh,cl, mfma(sl,ch,
// mfma(sh,ch, rr+cc))). |d_approx - d_ref| <= (rr+cc)*2^-12.4.
// Exactness restored structurally:
//   sweep1 (MFMA): per-point min of d_approx.
//   sweep2 (same MFMAs): collect all cands with d <= min + delta,
//     delta = (rr+ccmax)*2^-9 (>=5x error bound), into <=4 LDS slots
//     (E[size]~1.04; overflow -> full exact rescan, p~0).
//   R-phase: per-thread REFERENCE-EXACT fp32 tree eval of the shortlist,
//     winner = (min d_ref, lowest index) — set-based, atomic order-safe.
// Guarantees ref argmin exactly; quantized rebuilt by the proven replay
// kernel. No d_ws (R6 lesson). C/D mapping per m89/m91: col=lane&15,
// row=(lane>>4)*4+reg; A/B: row/col=lane&15, k=(lane>>4)*8+j.

#define RVQ_Q 10
#define RVQ_C 512
#define RVQ_D 32

static constexpr int  NPTS     = 262144;
static constexpr long IDX_OFF  = (long)NPTS * RVQ_D;
static constexpr long LOSS_OFF = IDX_OFF + (long)NPTS * RVQ_Q;
static constexpr int  BPTS     = 128;   // points per search block
static constexpr int  QC       = 128;   // candidates per staged quarter

typedef __attribute__((ext_vector_type(32))) float f32x32;
typedef __attribute__((ext_vector_type(8)))  short short8;
typedef __attribute__((ext_vector_type(4)))  float f32x4;

// ---------------------------------------------------------------------------
// reference-exact numpy reduction tree (proven absmax 0.0 in R1/R3-R10)
__device__ __forceinline__ float tree_dot(const f32x32& x, const f32x32& y) {
    float a[8];
#pragma unroll
    for (int j = 0; j < 8; ++j) a[j] = x[j] * y[j];
#pragma unroll
    for (int j = 8; j < RVQ_D; ++j) a[j & 7] = fmaf(x[j], y[j], a[j & 7]);
    return ((a[0] + a[1]) + (a[2] + a[3])) + ((a[4] + a[5]) + (a[6] + a[7]));
}

// bit-exact straight-through residual update
__device__ __forceinline__ f32x32 st_update(const f32x32& r, const f32x32& gv) {
    const f32x32 tt  = gv - r;
    const f32x32 qst = r + tt;
    return r - qst;
}

__device__ __forceinline__ short8 as_s8(uint4 u) {
    union { uint4 a; short8 b; } x; x.a = u; return x.b;
}

// pack two floats' bf16-truncations into one u32 (lo = v0, hi = v1)
__device__ __forceinline__ unsigned pk_hi(float v0, float v1) {
    return (__float_as_uint(v0) >> 16) | (__float_as_uint(v1) & 0xFFFF0000u);
}
__device__ __forceinline__ float lo_rem(float v) {  // v - bf16_trunc(v)
    return v - __uint_as_float(__float_as_uint(v) & 0xFFFF0000u);
}

// ---------------------------------------------------------------------------
__global__ __launch_bounds__(128, 2) void rvq_search(const float* __restrict__ z,
                                                     const float* __restrict__ cb,
                                                     float* __restrict__ out) {
    __shared__ uint4 ptfrag[BPTS * 8];        // 16 KB  point bf16 splits (-2r)
    __shared__ uint4 cfrag[QC * 8];           // 16 KB  candidate bf16 splits
    __shared__ float snorm[RVQ_C];            // 2 KB   exact-tree norms
    __shared__ float rrbuf[BPTS];
    __shared__ float thrbuf[BPTS];
    __shared__ unsigned cntbuf[BPTS];
    __shared__ unsigned short slotbuf[BPTS * 4];
    __shared__ int ccmax_i;

    const int t    = threadIdx.x;
    const int lane = t & 63;
    const int w    = t >> 6;        // wave 0/1
    const int col  = lane & 15;
    const int g    = lane >> 4;
    const int sw0  = g ^ (col & 7);        // swizzled chunk idx, split 0
    const int sw1  = (4 + g) ^ (col & 7);  // split 1
    const long p   = (long)blockIdx.x * BPTS + t;

    f32x32 r = *(const f32x32*)(z + p * RVQ_D);

#pragma unroll 1
    for (int q = 0; q < RVQ_Q; ++q) {
        const float* cbq = cb + (long)q * RVQ_C * RVQ_D;
        __syncthreads();   // prev stage's R-phase reads done

        // ---- E phase: rr, -2r bf16 split -> ptfrag, bookkeeping
        const float rr = tree_dot(r, r);
        rrbuf[t] = rr; cntbuf[t] = 0;
        if (t == 0) ccmax_i = 0;
        {
            const f32x32 s = -2.0f * r;
#pragma unroll
            for (int sp = 0; sp < 2; ++sp)
#pragma unroll
                for (int gg = 0; gg < 4; ++gg) {
                    unsigned u[4];
#pragma unroll
                    for (int pr = 0; pr < 4; ++pr) {
                        const int j = gg * 8 + pr * 2;
                        float v0 = s[j], v1 = s[j + 1];
                        if (sp == 1) { v0 = lo_rem(v0); v1 = lo_rem(v1); }
                        u[pr] = pk_hi(v0, v1);
                    }
                    ptfrag[t * 8 + ((sp * 4 + gg) ^ (t & 7))] =
                        make_uint4(u[0], u[1], u[2], u[3]);
                }
        }
        // ---- exact-tree norms (4 cands/thread) + ccmax
        {
            float cm = 0.0f;
#pragma unroll 1
            for (int n = 0; n < 4; ++n) {
                const int cnd = t + 128 * n;
                const f32x32 c = *(const f32x32*)(cbq + (long)cnd * RVQ_D);
                const float cc = tree_dot(c, c);
                snorm[cnd] = cc; cm = fmaxf(cm, cc);
            }
            atomicMax(&ccmax_i, __float_as_int(cm));
        }
        __syncthreads();

        // =================== SWEEP 1: per-point min of d_approx ============
        float runmin[4][4];
#pragma unroll
        for (int a = 0; a < 4; ++a)
#pragma unroll
            for (int b = 0; b < 4; ++b) runmin[a][b] = __builtin_inff();

#pragma unroll 1
        for (int qr = 0; qr < 4; ++qr) {
            __syncthreads();   // prev quarter's readers done
            {   // stage candidate quarter: thread t handles cand qr*128+t
                const f32x32 c = *(const f32x32*)(cbq + (long)(qr * QC + t) * RVQ_D);
#pragma unroll
                for (int sp = 0; sp < 2; ++sp)
#pragma unroll
                    for (int gg = 0; gg < 4; ++gg) {
                        unsigned u[4];
#pragma unroll
                        for (int pr = 0; pr < 4; ++pr) {
                            const int j = gg * 8 + pr * 2;
                            float v0 = c[j], v1 = c[j + 1];
                            if (sp == 1) { v0 = lo_rem(v0); v1 = lo_rem(v1); }
                            u[pr] = pk_hi(v0, v1);
                        }
                        cfrag[t * 8 + ((sp * 4 + gg) ^ (t & 7))] =
                            make_uint4(u[0], u[1], u[2], u[3]);
                    }
            }
            __syncthreads();

#pragma unroll 1
            for (int dual = 0; dual < 2; ++dual) {
                const int TA = w * 4 + dual * 2;        // block tile ids
                const int ptA = TA * 16 + col, ptB = (TA + 1) * 16 + col;
                const short8 ahA = as_s8(ptfrag[ptA * 8 + sw0]);
                const short8 alA = as_s8(ptfrag[ptA * 8 + sw1]);
                const short8 ahB = as_s8(ptfrag[ptB * 8 + sw0]);
                const short8 alB = as_s8(ptfrag[ptB * 8 + sw1]);
                float rrA[4], rrB[4];
#pragma unroll
                for (int i = 0; i < 4; ++i) {
                    rrA[i] = rrbuf[TA * 16 + 4 * g + i];
                    rrB[i] = rrbuf[(TA + 1) * 16 + 4 * g + i];
                }
#pragma unroll 2
                for (int ct = 0; ct < 8; ++ct) {
                    const int cl_ = ct * 16 + col;
                    const short8 bh = as_s8(cfrag[cl_ * 8 + sw0]);
                    const short8 bl = as_s8(cfrag[cl_ * 8 + sw1]);
                    const float ccv = snorm[qr * QC + cl_];
                    f32x4 acc = {rrA[0] + ccv, rrA[1] + ccv, rrA[2] + ccv, rrA[3] + ccv};
                    acc = __builtin_amdgcn_mfma_f32_16x16x32_bf16(ahA, bh, acc, 0, 0, 0);
                    acc = __builtin_amdgcn_mfma_f32_16x16x32_bf16(alA, bh, acc, 0, 0, 0);
                    acc = __builtin_amdgcn_mfma_f32_16x16x32_bf16(ahA, bl, acc, 0, 0, 0);
#pragma unroll
                    for (int i = 0; i < 4; ++i)
                        runmin[dual * 2][i] = fminf(runmin[dual * 2][i], acc[i]);
                    f32x4 acc2 = {rrB[0] + ccv, rrB[1] + ccv, rrB[2] + ccv, rrB[3] + ccv};
                    acc2 = __builtin_amdgcn_mfma_f32_16x16x32_bf16(ahB, bh, acc2, 0, 0, 0);
                    acc2 = __builtin_amdgcn_mfma_f32_16x16x32_bf16(alB, bh, acc2, 0, 0, 0);
                    acc2 = __builtin_amdgcn_mfma_f32_16x16x32_bf16(ahB, bl, acc2, 0, 0, 0);
#pragma unroll
                    for (int i = 0; i < 4; ++i)
                        runmin[dual * 2 + 1][i] = fminf(runmin[dual * 2 + 1][i], acc2[i]);
                }
            }
        }
        // ---- finalize: column-reduce min, write threshold
        {
            const float ccm = __int_as_float(ccmax_i);
#pragma unroll
            for (int tl = 0; tl < 4; ++tl)
#pragma unroll
                for (int i = 0; i < 4; ++i) {
                    float m = runmin[tl][i];
                    m = fminf(m, __shfl_xor(m, 1, 64));
                    m = fminf(m, __shfl_xor(m, 2, 64));
                    m = fminf(m, __shfl_xor(m, 4, 64));
                    m = fminf(m, __shfl_xor(m, 8, 64));
                    if (col == 0) {
                        const int ptl = (w * 4 + tl) * 16 + 4 * g + i;
                        thrbuf[ptl] = m + (rrbuf[ptl] + ccm) * 0.001953125f; // 2^-9
                    }
                }
        }
        __syncthreads();

        // =================== SWEEP 2: shortlist collection =================
#pragma unroll 1
        for (int qr = 0; qr < 4; ++qr) {
            __syncthreads();
            {   // restage (identical data -> identical accs)
                const f32x32 c = *(const f32x32*)(cbq + (long)(qr * QC + t) * RVQ_D);
#pragma unroll
                for (int sp = 0; sp < 2; ++sp)
#pragma unroll
                    for (int gg = 0; gg < 4; ++gg) {
                        unsigned u[4];
#pragma unroll
                        for (int pr = 0; pr < 4; ++pr) {
                            const int j = gg * 8 + pr * 2;
                            float v0 = c[j], v1 = c[j + 1];
                            if (sp == 1) { v0 = lo_rem(v0); v1 = lo_rem(v1); }
                            u[pr] = pk_hi(v0, v1);
                        }
                        cfrag[t * 8 + ((sp * 4 + gg) ^ (t & 7))] =
                            make_uint4(u[0], u[1], u[2], u[3]);
                    }
            }
            __syncthreads();

#pragma unroll 1
            for (int dual = 0; dual < 2; ++dual) {
                const int TA = w * 4 + dual * 2;
                const int ptA = TA * 16 + col, ptB = (TA + 1) * 16 + col;
                const short8 ahA = as_s8(ptfrag[ptA * 8 + sw0]);
                const short8 alA = as_s8(ptfrag[ptA * 8 + sw1]);
                const short8 ahB = as_s8(ptfrag[ptB * 8 + sw0]);
                const short8 alB = as_s8(ptfrag[ptB * 8 + sw1]);
                float rrA[4], rrB[4], thA[4], thB[4];
#pragma unroll
                for (int i = 0; i < 4; ++i) {
                    rrA[i] = rrbuf[TA * 16 + 4 * g + i];
                    rrB[i] = rrbuf[(TA + 1) * 16 + 4 * g + i];
                    thA[i] = thrbuf[TA * 16 + 4 * g + i];
                    thB[i] = thrbuf[(TA + 1) * 16 + 4 * g + i];
                }
#pragma unroll 2
                for (int ct = 0; ct < 8; ++ct) {
                    const int cl_ = ct * 16 + col;
                    const short8 bh = as_s8(cfrag[cl_ * 8 + sw0]);
                    const short8 bl = as_s8(cfrag[cl_ * 8 + sw1]);
                    const float ccv = snorm[qr * QC + cl_];
                    const unsigned short cgl = (unsigned short)(qr * QC + cl_);
                    f32x4 acc = {rrA[0] + ccv, rrA[1] + ccv, rrA[2] + ccv, rrA[3] + ccv};
                    acc = __builtin_amdgcn_mfma_f32_16x16x32_bf16(ahA, bh, acc, 0, 0, 0);
                    acc = __builtin_amdgcn_mfma_f32_16x16x32_bf16(alA, bh, acc, 0, 0, 0);
                    acc = __builtin_amdgcn_mfma_f32_16x16x32_bf16(ahA, bl, acc, 0, 0, 0);
#pragma unroll
                    for (int i = 0; i < 4; ++i)
                        if (acc[i] <= thA[i]) {
                            const int ptl = TA * 16 + 4 * g + i;
                            const unsigned sl_ = atomicAdd(&cntbuf[ptl], 1u);
                            if (sl_ < 4) slotbuf[ptl * 4 + sl_] = cgl;
                        }
                    f32x4 acc2 = {rrB[0] + ccv, rrB[1] + ccv, rrB[2] + ccv, rrB[3] + ccv};
                    acc2 = __builtin_amdgcn_mfma_f32_16x16x32_bf16(ahB, bh, acc2, 0, 0, 0);
                    acc2 = __builtin_amdgcn_mfma_f32_16x16x32_bf16(alB, bh, acc2, 0, 0, 0);
                    acc2 = __builtin_amdgcn_mfma_f32_16x16x32_bf16(ahB, bl, acc2, 0, 0, 0);
#pragma unroll
                    for (int i = 0; i < 4; ++i)
                        if (acc2[i] <= thB[i]) {
                            const int ptl = (TA + 1) * 16 + 4 * g + i;
                            const unsigned sl_ = atomicAdd(&cntbuf[ptl], 1u);
                            if (sl_ < 4) slotbuf[ptl * 4 + sl_] = cgl;
                        }
                }
            }
        }
        __syncthreads();

        // ---- R phase: reference-exact shortlist eval, idx out, update r
        {
            const unsigned n = cntbuf[t];
            float bd = __builtin_inff(); int bi = 0;
            if (n <= 4) {
#pragma unroll 1
                for (unsigned s_ = 0; s_ < n; ++s_) {
                    const int cnd = slotbuf[t * 4 + s_];
                    const f32x32 c = *(const f32x32*)(cbq + (long)cnd * RVQ_D);
                    const float cc  = tree_dot(c, c);
                    const float dot = tree_dot(r, c);
                    const float d   = fmaf(-2.0f, dot, rr) + cc;
                    if (d < bd || (d == bd && cnd < bi)) { bd = d; bi = cnd; }
                }
            } else {   // overflow (p~0): full reference-exact scan
#pragma unroll 1
                for (int cnd = 0; cnd < RVQ_C; ++cnd) {
                    const f32x32 c = *(const f32x32*)(cbq + (long)cnd * RVQ_D);
                    const float cc  = tree_dot(c, c);
                    const float dot = tree_dot(r, c);
                    const float d   = fmaf(-2.0f, dot, rr) + cc;
                    if (d < bd) { bd = d; bi = cnd; }
                }
            }
            out[IDX_OFF + p * RVQ_Q + q] = (float)bi;
            const f32x32 gw = *(const f32x32*)(cbq + (long)bi * RVQ_D);
            r = st_update(r, gw);
        }
    }
}

// ---------------------------------------------------------------------------
// Replay: bit-exact straight-through chain from stored indices (proven
// pre+post-timing R3-R10). Writes quantized + commit_loss.
__global__ __launch_bounds__(256) void rvq_replay(const float* __restrict__ z,
                                                  const float* __restrict__ cb,
                                                  float* __restrict__ out) {
    const int p = blockIdx.x * 256 + threadIdx.x;

    float r[RVQ_D], oacc[RVQ_D];
    {
        const float4* zp = (const float4*)(z + (long)p * RVQ_D);
#pragma unroll
        for (int w = 0; w < 8; ++w) {
            const float4 v = zp[w];
            r[w * 4 + 0] = v.x; r[w * 4 + 1] = v.y;
            r[w * 4 + 2] = v.z; r[w * 4 + 3] = v.w;
        }
    }
#pragma unroll
    for (int d = 0; d < RVQ_D; ++d) oacc[d] = 0.0f;

#pragma unroll 1
    for (int q = 0; q < RVQ_Q; ++q) {
        const int idx = (int)out[IDX_OFF + (long)p * RVQ_Q + q];
        const float4* cwb = (const float4*)(cb + ((long)q * RVQ_C + idx) * RVQ_D);
        float cwv[RVQ_D];
#pragma unroll
        for (int w = 0; w < 8; ++w) {
            const float4 v = cwb[w];
            cwv[w * 4 + 0] = v.x; cwv[w * 4 + 1] = v.y;
            cwv[w * 4 + 2] = v.z; cwv[w * 4 + 3] = v.w;
        }
#pragma unroll
        for (int d = 0; d < RVQ_D; ++d) {
            const float qst = r[d] + (cwv[d] - r[d]);
            oacc[d] += qst;
            r[d] = r[d] - qst;
        }
    }

    float4* qo = (float4*)(out + (long)p * RVQ_D);
#pragma unroll
    for (int w = 0; w < 8; ++w) {
        float4 v;
        v.x = oacc[w * 4 + 0]; v.y = oacc[w * 4 + 1];
        v.z = oacc[w * 4 + 2]; v.w = oacc[w * 4 + 3];
        qo[w] = v;
    }

    if (p < RVQ_Q) out[LOSS_OFF + p] = 0.0f;
}

// ---------------------------------------------------------------------------
extern "C" void kernel_launch(void* const* d_in, const int* in_sizes, int n_in,
                              void* d_out, int out_size, void* d_ws, size_t ws_size,
                              hipStream_t stream) {
    const float* z  = (const float*)d_in[0];
    const float* cb = (const float*)d_in[1];
    float* out = (float*)d_out;
    (void)d_ws; (void)ws_size;   // no workspace (R6 lesson)

    rvq_search<<<NPTS / BPTS, BPTS, 0, stream>>>(z, cb, out);
    rvq_replay<<<NPTS / 256, 256, 0, stream>>>(z, cb, out);
}